// Round 2
// baseline (495.366 us; speedup 1.0000x reference)
//
#include <hip/hip_runtime.h>
#include <hip/hip_bf16.h>

typedef __attribute__((ext_vector_type(8))) short bf16x8;
typedef __attribute__((ext_vector_type(4))) float f32x4;
typedef __attribute__((ext_vector_type(4))) short s16x4;

__device__ __forceinline__ short f2bf(float f) {
  union { float f; unsigned u; } v; v.f = f;
  unsigned r = v.u + 0x7fffu + ((v.u >> 16) & 1u);
  return (short)(r >> 16);
}

__device__ __forceinline__ float bf2f(short s) {
  union { float f; unsigned u; } v; v.u = ((unsigned)(unsigned short)s) << 16;
  return v.f;
}

#define GLD_LDS(g, l) __builtin_amdgcn_global_load_lds( \
    (const __attribute__((address_space(1))) void*)(g), \
    (__attribute__((address_space(3))) void*)(l), 16, 0, 0)

// ---------------- fp32 -> bf16 convert (x) ----------------
__global__ void convx_k(const float* __restrict__ x, short* __restrict__ xb, int n4) {
  int i = blockIdx.x * blockDim.x + threadIdx.x;
  const int stride = gridDim.x * blockDim.x;
  for (; i < n4; i += stride) {
    float4 v = ((const float4*)x)[i];
    s16x4 o;
    o[0] = f2bf(v.x); o[1] = f2bf(v.y); o[2] = f2bf(v.z); o[3] = f2bf(v.w);
    ((s16x4*)xb)[i] = o;
  }
}

// ---------------- transpose + convert weights: Wt[d][c] = W[c][d] ----------------
__global__ void twc_k(const float* __restrict__ Wq, const float* __restrict__ Wk,
                      const float* __restrict__ Wv, const float* __restrict__ Wo,
                      short* __restrict__ dst) {
  __shared__ float tile[32][33];
  const int z = blockIdx.z;
  const float* src = (z == 0) ? Wq
                   : (z == 1) ? Wk
                   : (z == 2) ? (Wk + 1048576)
                   : (z == 3) ? Wv
                   : (z == 4) ? (Wv + 1048576)
                   : Wo;
  short* d = dst + (size_t)z * 1048576;
  const int tx = threadIdx.x, ty = threadIdx.y;
  const int c0 = blockIdx.y * 32, d0 = blockIdx.x * 32;
#pragma unroll
  for (int i = 0; i < 4; ++i)
    tile[ty + i * 8][tx] = src[(size_t)(c0 + ty + i * 8) * 1024 + d0 + tx];
  __syncthreads();
#pragma unroll
  for (int i = 0; i < 4; ++i)
    d[(size_t)(d0 + ty + i * 8) * 1024 + c0 + tx] = f2bf(tile[tx][ty + i * 8]);
}

// ---------------- fused input-projection GEMM ----------------
// D[16384 x 5120] = xb @ [Wq|Wk0|Wk1|Wv0|Wv1]^T, + resid(bf16 xb) + bias.
// w==0 -> q bf16 [row][col];  w in 1..4 -> transposed scaled bf16 [kv, bh, d, n].
__global__ __launch_bounds__(256)
void gemm5_k(const short* __restrict__ A, const short* __restrict__ Wt,
             const float* __restrict__ bq, const float* __restrict__ bk,
             const float* __restrict__ bv,
             short* __restrict__ q, short* __restrict__ kvt) {
  __shared__ short Ab[2][4096];
  __shared__ short Bb[2][4096];
  const int bid = blockIdx.x;                 // 0..5119
  const int swz = (bid & 7) * 640 + (bid >> 3);  // XCD-chunked, bijective (5120%8==0)
  const int bm = swz / 40;                    // 0..127  (m-major: 40 consecutive share A slab)
  const int bng = swz % 40;                   // 0..39
  const int w = bng >> 3;                     // which weight 0..4
  const int bn0 = (bng & 7) << 7;             // col offset within this weight
  const int bm0 = bm << 7;
  const short* Bt = Wt + ((size_t)w << 20);

  const int tid = threadIdx.x;
  const int lane = tid & 63;
  const int wid = tid >> 6;
  const int wm = (wid >> 1) << 6;
  const int wn = (wid & 1) << 6;
  const int K = 1024;
  const int srow = lane >> 2;
  const int sk = (lane & 3) << 3;

  f32x4 acc[4][4];
#pragma unroll
  for (int i = 0; i < 4; ++i)
#pragma unroll
    for (int j = 0; j < 4; ++j) acc[i][j] = f32x4{0.f, 0.f, 0.f, 0.f};

  auto stage = [&](int buf, int t) {
    const int k0 = t << 5;
#pragma unroll
    for (int c2 = 0; c2 < 2; ++c2) {
      const int s = wid * 2 + c2;
      const short* ga = A + (size_t)(bm0 + s * 16 + srow) * K + (k0 + sk);
      GLD_LDS(ga, &Ab[buf][s << 9]);
      const short* gb = Bt + (size_t)(bn0 + s * 16 + srow) * K + (k0 + sk);
      GLD_LDS(gb, &Bb[buf][s << 9]);
    }
  };

  stage(0, 0);
  __syncthreads();
#pragma unroll 1
  for (int t = 0; t < 32; ++t) {
    const int cur = t & 1;
    if (t < 31) stage(cur ^ 1, t + 1);
    const short* ab = Ab[cur];
    const short* bbp = Bb[cur];
    bf16x8 af[4], bfr[4];
#pragma unroll
    for (int i = 0; i < 4; ++i)
      af[i] = *(const bf16x8*)(ab + ((wm + i * 16 + (lane & 15)) << 5) + ((lane >> 4) << 3));
#pragma unroll
    for (int j = 0; j < 4; ++j)
      bfr[j] = *(const bf16x8*)(bbp + ((wn + j * 16 + (lane & 15)) << 5) + ((lane >> 4) << 3));
#pragma unroll
    for (int i = 0; i < 4; ++i)
#pragma unroll
      for (int j = 0; j < 4; ++j)
        acc[i][j] = __builtin_amdgcn_mfma_f32_16x16x32_bf16(af[i], bfr[j], acc[i][j], 0, 0, 0);
    __syncthreads();
  }

  const float scale = (w == 0) ? 1.0f : 0.015625f;  // 1/sqrt(4096)
  const float* bias = (w == 0) ? bq : (w <= 2) ? bk + ((w - 1) << 10) : bv + ((w - 3) << 10);
  short* kdst = kvt + (((size_t)(w - 1)) << 24);

  const int cl = lane & 15;
  const int r0 = bm0 + wm + ((lane >> 4) << 2);
#pragma unroll
  for (int i = 0; i < 4; ++i) {
#pragma unroll
    for (int j = 0; j < 4; ++j) {
      const int col = bn0 + wn + j * 16 + cl;
      const int rowb = r0 + i * 16;
      const float bi = bias[col];
      if (w == 0) {
#pragma unroll
        for (int r = 0; r < 4; ++r) {
          const float v = acc[i][j][r] + bf2f(A[(size_t)(rowb + r) * 1024 + col]) + bi;
          q[(size_t)(rowb + r) * 1024 + col] = f2bf(v);
        }
      } else {
        s16x4 pk;
#pragma unroll
        for (int r = 0; r < 4; ++r) {
          const float v = (acc[i][j][r] + bf2f(A[(size_t)(rowb + r) * 1024 + col]) + bi) * scale;
          pk[r] = f2bf(v);
        }
        const int b = rowb >> 12;
        const int nn = rowb & 4095;
        const int h = col >> 6, dd = col & 63;
        *(s16x4*)(kdst + (((size_t)((b * 16 + h) * 64 + dd)) << 12) + nn) = pk;
      }
    }
  }
}

// ---------------- final GEMM: out fp32 = ln(bf16) @ Wo^T + bo ----------------
__global__ __launch_bounds__(256)
void gemmo_k(const short* __restrict__ A, const short* __restrict__ Bt,
             const float* __restrict__ bias, float* __restrict__ outp) {
  __shared__ short Ab[2][4096];
  __shared__ short Bb[2][4096];
  const int bid = blockIdx.x;                  // 0..1023
  const int swz = (bid & 7) * 128 + (bid >> 3);
  const int bm0 = (swz >> 3) << 7;
  const int bn0 = (swz & 7) << 7;
  const int tid = threadIdx.x;
  const int lane = tid & 63;
  const int wid = tid >> 6;
  const int wm = (wid >> 1) << 6;
  const int wn = (wid & 1) << 6;
  const int K = 1024;
  const int srow = lane >> 2;
  const int sk = (lane & 3) << 3;

  f32x4 acc[4][4];
#pragma unroll
  for (int i = 0; i < 4; ++i)
#pragma unroll
    for (int j = 0; j < 4; ++j) acc[i][j] = f32x4{0.f, 0.f, 0.f, 0.f};

  auto stage = [&](int buf, int t) {
    const int k0 = t << 5;
#pragma unroll
    for (int c2 = 0; c2 < 2; ++c2) {
      const int s = wid * 2 + c2;
      const short* ga = A + (size_t)(bm0 + s * 16 + srow) * K + (k0 + sk);
      GLD_LDS(ga, &Ab[buf][s << 9]);
      const short* gb = Bt + (size_t)(bn0 + s * 16 + srow) * K + (k0 + sk);
      GLD_LDS(gb, &Bb[buf][s << 9]);
    }
  };

  stage(0, 0);
  __syncthreads();
#pragma unroll 1
  for (int t = 0; t < 32; ++t) {
    const int cur = t & 1;
    if (t < 31) stage(cur ^ 1, t + 1);
    const short* ab = Ab[cur];
    const short* bbp = Bb[cur];
    bf16x8 af[4], bfr[4];
#pragma unroll
    for (int i = 0; i < 4; ++i)
      af[i] = *(const bf16x8*)(ab + ((wm + i * 16 + (lane & 15)) << 5) + ((lane >> 4) << 3));
#pragma unroll
    for (int j = 0; j < 4; ++j)
      bfr[j] = *(const bf16x8*)(bbp + ((wn + j * 16 + (lane & 15)) << 5) + ((lane >> 4) << 3));
#pragma unroll
    for (int i = 0; i < 4; ++i)
#pragma unroll
      for (int j = 0; j < 4; ++j)
        acc[i][j] = __builtin_amdgcn_mfma_f32_16x16x32_bf16(af[i], bfr[j], acc[i][j], 0, 0, 0);
    __syncthreads();
  }

  const int cl = lane & 15;
  const int r0 = bm0 + wm + ((lane >> 4) << 2);
#pragma unroll
  for (int i = 0; i < 4; ++i)
#pragma unroll
    for (int j = 0; j < 4; ++j) {
      const int col = bn0 + wn + j * 16 + cl;
      const int rowb = r0 + i * 16;
      const float bi = bias[col];
#pragma unroll
      for (int r = 0; r < 4; ++r)
        outp[(size_t)(rowb + r) * 1024 + col] = acc[i][j][r] + bi;
    }
}

// ---------------- states partials: P[c][k][bh][d][e] += ks^T * vs over n-chunk ----------------
__global__ __launch_bounds__(256)
void states_k(const short* __restrict__ kst, const short* __restrict__ vst,
              float* __restrict__ P) {
  __shared__ short Al[64 * 40];
  __shared__ short Bl[64 * 40];
  const int tid = threadIdx.x;
  const int lane = tid & 63;
  const int wid = tid >> 6;
  const int bh = blockIdx.x;
  const int ch = blockIdx.y;
  const int kk = blockIdx.z;
  const size_t base = ((size_t)(kk * 64 + bh)) << 18;
  const int n0 = ch << 10;
  const int srow = tid >> 2;
  const int sch = (tid & 3) << 3;
  const size_t soff = base + (size_t)srow * 4096 + n0 + sch;

  f32x4 acc[4];
#pragma unroll
  for (int j = 0; j < 4; ++j) acc[j] = f32x4{0.f, 0.f, 0.f, 0.f};

#pragma unroll 1
  for (int ns = 0; ns < 1024; ns += 32) {
    bf16x8 va = *(const bf16x8*)(kst + soff + ns);
    bf16x8 vb = *(const bf16x8*)(vst + soff + ns);
    __syncthreads();
    *(bf16x8*)(Al + srow * 40 + sch) = va;
    *(bf16x8*)(Bl + srow * 40 + sch) = vb;
    __syncthreads();
    bf16x8 a = *(const bf16x8*)(Al + (wid * 16 + (lane & 15)) * 40 + ((lane >> 4) << 3));
#pragma unroll
    for (int j = 0; j < 4; ++j) {
      bf16x8 b = *(const bf16x8*)(Bl + (j * 16 + (lane & 15)) * 40 + ((lane >> 4) << 3));
      acc[j] = __builtin_amdgcn_mfma_f32_16x16x32_bf16(a, b, acc[j], 0, 0, 0);
    }
  }
  const size_t pb = ((size_t)((ch * 2 + kk) * 64 + bh)) << 12;
  const int r0 = wid * 16 + ((lane >> 4) << 2);
  const int cl = lane & 15;
#pragma unroll
  for (int j = 0; j < 4; ++j)
#pragma unroll
    for (int r = 0; r < 4; ++r)
      P[pb + (size_t)(r0 + r) * 64 + j * 16 + cl] = acc[j][r];
}

// ---------------- reduce chunks, state = S0*S1, write transposed bf16 ----------------
__global__ __launch_bounds__(256)
void state_mul_k(const float* __restrict__ P, short* __restrict__ stt) {
  const int bh = blockIdx.x;
  for (int t = threadIdx.x; t < 4096; t += 256) {
    float s0 = 0.f, s1 = 0.f;
#pragma unroll
    for (int c = 0; c < 4; ++c) {
      s0 += P[(((size_t)((c * 2 + 0) * 64 + bh)) << 12) + t];
      s1 += P[(((size_t)((c * 2 + 1) * 64 + bh)) << 12) + t];
    }
    const int d = t >> 6, e = t & 63;
    stt[(bh << 12) + (e << 6) + d] = f2bf(s0 * s1);
  }
}

// ---------------- out_att = q @ state per (b,h) ----------------
__global__ __launch_bounds__(256)
void attn_k(const short* __restrict__ q, const short* __restrict__ stt,
            float* __restrict__ oat) {
  __shared__ short Al[128 * 72];
  __shared__ short Bl[64 * 72];
  const int tid = threadIdx.x;
  const int lane = tid & 63;
  const int wid = tid >> 6;
  const int mc = blockIdx.x;
  const int bh = blockIdx.y;
  const int b = bh >> 4, h = bh & 15;
  const size_t qbase = ((size_t)(b * 4096 + mc * 128)) * 1024 + h * 64;
#pragma unroll
  for (int s = 0; s < 4; ++s) {
    const int idx = tid + s * 256;
    const int row = idx >> 3, cc = (idx & 7) << 3;
    *(bf16x8*)(Al + row * 72 + cc) = *(const bf16x8*)(q + qbase + (size_t)row * 1024 + cc);
  }
#pragma unroll
  for (int s = 0; s < 2; ++s) {
    const int idx = tid + s * 256;
    const int row = idx >> 3, cc = (idx & 7) << 3;
    *(bf16x8*)(Bl + row * 72 + cc) = *(const bf16x8*)(stt + (bh << 12) + (row << 6) + cc);
  }
  __syncthreads();
  f32x4 acc[2][4];
#pragma unroll
  for (int i = 0; i < 2; ++i)
#pragma unroll
    for (int j = 0; j < 4; ++j) acc[i][j] = f32x4{0.f, 0.f, 0.f, 0.f};
#pragma unroll
  for (int ks = 0; ks < 2; ++ks) {
    bf16x8 a0 = *(const bf16x8*)(Al + (wid * 32 + (lane & 15)) * 72 + ks * 32 + ((lane >> 4) << 3));
    bf16x8 a1 = *(const bf16x8*)(Al + (wid * 32 + 16 + (lane & 15)) * 72 + ks * 32 + ((lane >> 4) << 3));
#pragma unroll
    for (int j = 0; j < 4; ++j) {
      bf16x8 bb = *(const bf16x8*)(Bl + (j * 16 + (lane & 15)) * 72 + ks * 32 + ((lane >> 4) << 3));
      acc[0][j] = __builtin_amdgcn_mfma_f32_16x16x32_bf16(a0, bb, acc[0][j], 0, 0, 0);
      acc[1][j] = __builtin_amdgcn_mfma_f32_16x16x32_bf16(a1, bb, acc[1][j], 0, 0, 0);
    }
  }
  const int r0 = wid * 32 + ((lane >> 4) << 2);
  const int cl = lane & 15;
#pragma unroll
  for (int i = 0; i < 2; ++i)
#pragma unroll
    for (int j = 0; j < 4; ++j)
#pragma unroll
      for (int r = 0; r < 4; ++r) {
        const int row = b * 4096 + mc * 128 + r0 + i * 16 + r;
        oat[(size_t)row * 1024 + h * 64 + j * 16 + cl] = acc[i][j][r];
      }
}

// ---------------- LayerNorm over C=1024, fp32 in -> bf16 out ----------------
__global__ __launch_bounds__(256)
void ln_k(const float* __restrict__ in, const float* __restrict__ g,
          const float* __restrict__ bb, short* __restrict__ out) {
  const int row = blockIdx.x;
  const int tid = threadIdx.x;
  const float4 v = ((const float4*)(in + (size_t)row * 1024))[tid];
  float s = v.x + v.y + v.z + v.w;
  float s2 = v.x * v.x + v.y * v.y + v.z * v.z + v.w * v.w;
#pragma unroll
  for (int o = 32; o > 0; o >>= 1) {
    s += __shfl_down(s, o);
    s2 += __shfl_down(s2, o);
  }
  __shared__ float red[8];
  const int wid = tid >> 6, lane = tid & 63;
  if (lane == 0) { red[wid] = s; red[wid + 4] = s2; }
  __syncthreads();
  const float ts = red[0] + red[1] + red[2] + red[3];
  const float ts2 = red[4] + red[5] + red[6] + red[7];
  const float mu = ts * (1.0f / 1024.0f);
  const float var = ts2 * (1.0f / 1024.0f) - mu * mu;
  const float rstd = rsqrtf(var + 1e-5f);
  const int c = tid * 4;
  s16x4 o;
  o[0] = f2bf((v.x - mu) * rstd * g[c + 0] + bb[c + 0]);
  o[1] = f2bf((v.y - mu) * rstd * g[c + 1] + bb[c + 1]);
  o[2] = f2bf((v.z - mu) * rstd * g[c + 2] + bb[c + 2]);
  o[3] = f2bf((v.w - mu) * rstd * g[c + 3] + bb[c + 3]);
  *(s16x4*)(out + (size_t)row * 1024 + c) = o;
}

extern "C" void kernel_launch(void* const* d_in, const int* in_sizes, int n_in,
                              void* d_out, int out_size, void* d_ws, size_t ws_size,
                              hipStream_t stream) {
  const float* x = (const float*)d_in[0];
  const float* Wq = (const float*)d_in[1];
  const float* bq = (const float*)d_in[2];
  const float* Wk = (const float*)d_in[3];
  const float* bk = (const float*)d_in[4];
  const float* Wv = (const float*)d_in[5];
  const float* bv = (const float*)d_in[6];
  const float* Wo = (const float*)d_in[7];
  const float* bo = (const float*)d_in[8];
  const float* lng = (const float*)d_in[9];
  const float* lnb = (const float*)d_in[10];

  char* ws = (char*)d_ws;
  short* xb = (short*)(ws + 0);              // 33554432 B  x bf16
  short* wt = (short*)(ws + 33554432);       // 12582912 B  6x W^T bf16
  short* q = (short*)(ws + 46137344);        // 33554432 B  q bf16
  short* kst = (short*)(ws + 79691776);      // 67108864 B  ks_t bf16 [k,b,h,d,n]
  short* vst = (short*)(ws + 146800640);     // 67108864 B  vs_t bf16
  float* P = (float*)(ws + 213909504);       //  8388608 B  state partials fp32
  short* stt = (short*)(ws + 222298112);     //   524288 B  state^T bf16
  short* ln = (short*)(ws + 146800640);      // reuse vst region (dead after states_k)
  float* oat = (float*)d_out;                // out_att scratch in d_out (overwritten by final GEMM)

  convx_k<<<4096, 256, 0, stream>>>(x, xb, 16777216 / 4);
  twc_k<<<dim3(32, 32, 6), dim3(32, 8), 0, stream>>>(Wq, Wk, Wv, Wo, wt);

  gemm5_k<<<5120, 256, 0, stream>>>(xb, wt, bq, bk, bv, q, kst);

  states_k<<<dim3(64, 4, 2), 256, 0, stream>>>(kst, vst, P);
  state_mul_k<<<64, 256, 0, stream>>>(P, stt);
  attn_k<<<dim3(32, 64), 256, 0, stream>>>(q, stt, oat);
  ln_k<<<16384, 256, 0, stream>>>(oat, lng, lnb, ln);
  gemmo_k<<<1024, 256, 0, stream>>>(ln, wt + 5242880, bo, (float*)d_out);
}

// Round 3
// 324.817 us; speedup vs baseline: 1.5251x; 1.5251x over previous
//
#include <hip/hip_runtime.h>
#include <hip/hip_bf16.h>

typedef __attribute__((ext_vector_type(8))) short bf16x8;
typedef __attribute__((ext_vector_type(4))) float f32x4;
typedef __attribute__((ext_vector_type(4))) short s16x4;

__device__ __forceinline__ short f2bf(float f) {
  union { float f; unsigned u; } v; v.f = f;
  unsigned r = v.u + 0x7fffu + ((v.u >> 16) & 1u);
  return (short)(r >> 16);
}

__device__ __forceinline__ float bf2f(short s) {
  union { float f; unsigned u; } v; v.u = ((unsigned)(unsigned short)s) << 16;
  return v.f;
}

#define GLD_LDS(g, l) __builtin_amdgcn_global_load_lds( \
    (const __attribute__((address_space(1))) void*)(g), \
    (__attribute__((address_space(3))) void*)(l), 16, 0, 0)

// ---------------- fp32 -> bf16 convert (x) ----------------
__global__ void convx_k(const float* __restrict__ x, short* __restrict__ xb, int n4) {
  int i = blockIdx.x * blockDim.x + threadIdx.x;
  const int stride = gridDim.x * blockDim.x;
  for (; i < n4; i += stride) {
    float4 v = ((const float4*)x)[i];
    s16x4 o;
    o[0] = f2bf(v.x); o[1] = f2bf(v.y); o[2] = f2bf(v.z); o[3] = f2bf(v.w);
    ((s16x4*)xb)[i] = o;
  }
}

// ---------------- transpose + convert weights: Wt[d][c] = W[c][d] (+I for z<5) ----------------
__global__ void twc_k(const float* __restrict__ Wq, const float* __restrict__ Wk,
                      const float* __restrict__ Wv, const float* __restrict__ Wo,
                      short* __restrict__ dst) {
  __shared__ float tile[32][33];
  const int z = blockIdx.z;
  const float* src = (z == 0) ? Wq
                   : (z == 1) ? Wk
                   : (z == 2) ? (Wk + 1048576)
                   : (z == 3) ? Wv
                   : (z == 4) ? (Wv + 1048576)
                   : Wo;
  short* d = dst + (size_t)z * 1048576;
  const int tx = threadIdx.x, ty = threadIdx.y;
  const int c0 = blockIdx.y * 32, d0 = blockIdx.x * 32;
#pragma unroll
  for (int i = 0; i < 4; ++i)
    tile[ty + i * 8][tx] = src[(size_t)(c0 + ty + i * 8) * 1024 + d0 + tx];
  __syncthreads();
#pragma unroll
  for (int i = 0; i < 4; ++i) {
    const int cc = c0 + tx;
    const int dd = d0 + ty + i * 8;
    float v = tile[tx][ty + i * 8];
    if (z < 5 && cc == dd) v += 1.0f;  // fold residual: x + x@W = x@(I+W)
    d[(size_t)dd * 1024 + cc] = f2bf(v);
  }
}

// ---------------- 256x256-tile BK=64 2-phase GEMM ----------------
// MODE 0: fused 5-proj. w==0 -> q bf16 row-major; w>=1 -> kv bf16 transposed
//         [kv,b,h,d,n] via LDS-bounce coalesced store, scaled.
// MODE 1: final GEMM, fp32 out = A@WT^T + bias.
// LDS swizzle: global source pre-permuted so LDS dest stays linear for
// global_load_lds; ds_read applies matching XOR (rule #21 both-sides).
template <int MODE>
__global__ __launch_bounds__(512, 2)
void gemm256_k(const short* __restrict__ A, const short* __restrict__ WT,
               const float* __restrict__ bq, const float* __restrict__ bk,
               const float* __restrict__ bv,
               short* __restrict__ q, short* __restrict__ kvt,
               float* __restrict__ fout) {
  extern __shared__ short lds[];  // 131072 B
  const int tid = threadIdx.x;
  const int lane = tid & 63;
  const int wv = tid >> 6;   // 0..7
  const int wm = wv >> 2;    // 0..1
  const int wn = wv & 3;     // 0..3

  int bm, w, bn;
  if (MODE == 0) {
    const int swz = (blockIdx.x & 7) * 160 + (blockIdx.x >> 3);  // XCD-bijective (1280%8==0)
    const int bng = swz >> 6;  // 0..19  (64 consecutive share B-tile -> L2 resident)
    bm = swz & 63;
    w = bng / 4; bn = bng & 3;
  } else {
    const int swz = (blockIdx.x & 7) * 32 + (blockIdx.x >> 3);   // 256 blocks
    bm = swz & 63; bn = swz >> 6; w = 0;
  }
  const int bm0 = bm << 8;
  const int bn0 = bn << 8;
  const short* Bt = WT + ((size_t)w << 20);

  const int l8 = lane >> 3;
  const int kperm = ((lane & 7) ^ l8) << 3;  // pre-swizzled source k-offset (shorts)

  f32x4 acc[8][4];
#pragma unroll
  for (int i = 0; i < 8; ++i)
#pragma unroll
    for (int j = 0; j < 4; ++j) acc[i][j] = f32x4{0.f, 0.f, 0.f, 0.f};

  auto stage = [&](int buf, int t) {
    const int k0 = t << 6;
    short* ab = lds + (buf << 14);
    short* bb = lds + 32768 + (buf << 14);
#pragma unroll
    for (int c = 0; c < 4; ++c) {
      const int r8 = (wv * 4 + c) * 8;  // 8-row group base
      const short* ga = A + (size_t)(bm0 + r8 + l8) * 1024 + k0 + kperm;
      GLD_LDS(ga, ab + (r8 << 6));
      const short* gb = Bt + (size_t)(bn0 + r8 + l8) * 1024 + k0 + kperm;
      GLD_LDS(gb, bb + (r8 << 6));
    }
  };

  const int cl = lane & 15;
  const int khi = lane >> 4;  // 0..3

  auto compute = [&](int buf) {
    const short* ab = lds + (buf << 14);
    const short* bb = lds + 32768 + (buf << 14);
#pragma unroll
    for (int ks = 0; ks < 2; ++ks) {
      const int k16 = (ks << 2) + khi;  // 0..7 (16B units)
      bf16x8 af[8], bfr[4];
#pragma unroll
      for (int i = 0; i < 8; ++i) {
        const int R = (wm << 7) + (i << 4) + cl;
        af[i] = *(const bf16x8*)(ab + (R << 6) + ((k16 ^ (R & 7)) << 3));
      }
#pragma unroll
      for (int j = 0; j < 4; ++j) {
        const int C = (wn << 6) + (j << 4) + cl;
        bfr[j] = *(const bf16x8*)(bb + (C << 6) + ((k16 ^ (C & 7)) << 3));
      }
#pragma unroll
      for (int i = 0; i < 8; ++i)
#pragma unroll
        for (int j = 0; j < 4; ++j)
          acc[i][j] = __builtin_amdgcn_mfma_f32_16x16x32_bf16(af[i], bfr[j], acc[i][j], 0, 0, 0);
    }
  };

  stage(0, 0);
  __syncthreads();
#pragma unroll 1
  for (int t = 0; t < 15; ++t) {
    const int cur = t & 1;
    stage(cur ^ 1, t + 1);
    compute(cur);
    __syncthreads();
  }
  compute(1);

  if (MODE == 1) {
#pragma unroll
    for (int i = 0; i < 8; ++i)
#pragma unroll
      for (int j = 0; j < 4; ++j) {
        const int col = bn0 + (wn << 6) + (j << 4) + cl;
        const int rowb = bm0 + (wm << 7) + (i << 4) + (khi << 2);
        const float bi = bq[col];
#pragma unroll
        for (int r = 0; r < 4; ++r)
          fout[(size_t)(rowb + r) * 1024 + col] = acc[i][j][r] + bi;
      }
    return;
  }

  if (w == 0) {
#pragma unroll
    for (int i = 0; i < 8; ++i)
#pragma unroll
      for (int j = 0; j < 4; ++j) {
        const int col = bn0 + (wn << 6) + (j << 4) + cl;
        const int rowb = bm0 + (wm << 7) + (i << 4) + (khi << 2);
        const float bi = bq[col];
#pragma unroll
        for (int r = 0; r < 4; ++r)
          q[(size_t)(rowb + r) * 1024 + col] = f2bf(acc[i][j][r] + bi);
      }
    return;
  }

  // kv: transposed coalesced store via LDS bounce
  __syncthreads();  // K-loop LDS reads done before reuse
  const float scale = 0.015625f;  // 1/sqrt(4096)
  const float* bias = (w <= 2) ? bk + ((w - 1) << 10) : bv + ((w - 3) << 10);
  short* kdst = kvt + (((size_t)(w - 1)) << 24);
  const int b = bm0 >> 12;
  const int nb = bm0 & 4095;
#pragma unroll 1
  for (int ch = 0; ch < 2; ++ch) {
    if ((wn >> 1) == ch) {
#pragma unroll
      for (int i = 0; i < 8; ++i)
#pragma unroll
        for (int j = 0; j < 4; ++j) {
          const int lcol = ((wn & 1) << 6) + (j << 4) + cl;       // 0..127
          const int lrow = (wm << 7) + (i << 4) + (khi << 2);     // 0..252
          const float bi = bias[bn0 + (ch << 7) + lcol];
          s16x4 pk;
#pragma unroll
          for (int r = 0; r < 4; ++r) pk[r] = f2bf((acc[i][j][r] + bi) * scale);
          *(s16x4*)(lds + lcol * 260 + lrow) = pk;
        }
    }
    __syncthreads();
#pragma unroll
    for (int it = 0; it < 16; ++it) {
      const int lcol = (it << 3) + wv;
      const int n0 = lane << 2;
      const s16x4 pk = *(const s16x4*)(lds + lcol * 260 + n0);
      const int colg = bn0 + (ch << 7) + lcol;
      const int h = colg >> 6, dd = colg & 63;
      *(s16x4*)(kdst + (((size_t)((b * 16 + h) * 64 + dd)) << 12) + nb + n0) = pk;
    }
    __syncthreads();
  }
}

// ---------------- states partials: P[c][k][bh][d][e] += ks^T * vs over n-chunk ----------------
__global__ __launch_bounds__(256)
void states_k(const short* __restrict__ kst, const short* __restrict__ vst,
              float* __restrict__ P) {
  __shared__ short Al[64 * 40];
  __shared__ short Bl[64 * 40];
  const int tid = threadIdx.x;
  const int lane = tid & 63;
  const int wid = tid >> 6;
  const int bh = blockIdx.x;
  const int ch = blockIdx.y;
  const int kk = blockIdx.z;
  const size_t base = ((size_t)(kk * 64 + bh)) << 18;
  const int n0 = ch << 10;
  const int srow = tid >> 2;
  const int sch = (tid & 3) << 3;
  const size_t soff = base + (size_t)srow * 4096 + n0 + sch;

  f32x4 acc[4];
#pragma unroll
  for (int j = 0; j < 4; ++j) acc[j] = f32x4{0.f, 0.f, 0.f, 0.f};

#pragma unroll 1
  for (int ns = 0; ns < 1024; ns += 32) {
    bf16x8 va = *(const bf16x8*)(kst + soff + ns);
    bf16x8 vb = *(const bf16x8*)(vst + soff + ns);
    __syncthreads();
    *(bf16x8*)(Al + srow * 40 + sch) = va;
    *(bf16x8*)(Bl + srow * 40 + sch) = vb;
    __syncthreads();
    bf16x8 a = *(const bf16x8*)(Al + (wid * 16 + (lane & 15)) * 40 + ((lane >> 4) << 3));
#pragma unroll
    for (int j = 0; j < 4; ++j) {
      bf16x8 b = *(const bf16x8*)(Bl + (j * 16 + (lane & 15)) * 40 + ((lane >> 4) << 3));
      acc[j] = __builtin_amdgcn_mfma_f32_16x16x32_bf16(a, b, acc[j], 0, 0, 0);
    }
  }
  const size_t pb = ((size_t)((ch * 2 + kk) * 64 + bh)) << 12;
  const int r0 = wid * 16 + ((lane >> 4) << 2);
  const int cl = lane & 15;
#pragma unroll
  for (int j = 0; j < 4; ++j)
#pragma unroll
    for (int r = 0; r < 4; ++r)
      P[pb + (size_t)(r0 + r) * 64 + j * 16 + cl] = acc[j][r];
}

// ---------------- reduce chunks, state = S0*S1, write transposed bf16 ----------------
__global__ __launch_bounds__(256)
void state_mul_k(const float* __restrict__ P, short* __restrict__ stt) {
  const int bh = blockIdx.x;
  for (int t = threadIdx.x; t < 4096; t += 256) {
    float s0 = 0.f, s1 = 0.f;
#pragma unroll
    for (int c = 0; c < 4; ++c) {
      s0 += P[(((size_t)((c * 2 + 0) * 64 + bh)) << 12) + t];
      s1 += P[(((size_t)((c * 2 + 1) * 64 + bh)) << 12) + t];
    }
    const int d = t >> 6, e = t & 63;
    stt[(bh << 12) + (e << 6) + d] = f2bf(s0 * s1);
  }
}

// ---------------- out_att = q @ state per (b,h) ----------------
__global__ __launch_bounds__(256)
void attn_k(const short* __restrict__ q, const short* __restrict__ stt,
            float* __restrict__ oat) {
  __shared__ short Al[128 * 72];
  __shared__ short Bl[64 * 72];
  const int tid = threadIdx.x;
  const int lane = tid & 63;
  const int wid = tid >> 6;
  const int mc = blockIdx.x;
  const int bh = blockIdx.y;
  const int b = bh >> 4, h = bh & 15;
  const size_t qbase = ((size_t)(b * 4096 + mc * 128)) * 1024 + h * 64;
#pragma unroll
  for (int s = 0; s < 4; ++s) {
    const int idx = tid + s * 256;
    const int row = idx >> 3, cc = (idx & 7) << 3;
    *(bf16x8*)(Al + row * 72 + cc) = *(const bf16x8*)(q + qbase + (size_t)row * 1024 + cc);
  }
#pragma unroll
  for (int s = 0; s < 2; ++s) {
    const int idx = tid + s * 256;
    const int row = idx >> 3, cc = (idx & 7) << 3;
    *(bf16x8*)(Bl + row * 72 + cc) = *(const bf16x8*)(stt + (bh << 12) + (row << 6) + cc);
  }
  __syncthreads();
  f32x4 acc[2][4];
#pragma unroll
  for (int i = 0; i < 2; ++i)
#pragma unroll
    for (int j = 0; j < 4; ++j) acc[i][j] = f32x4{0.f, 0.f, 0.f, 0.f};
#pragma unroll
  for (int ks = 0; ks < 2; ++ks) {
    bf16x8 a0 = *(const bf16x8*)(Al + (wid * 32 + (lane & 15)) * 72 + ks * 32 + ((lane >> 4) << 3));
    bf16x8 a1 = *(const bf16x8*)(Al + (wid * 32 + 16 + (lane & 15)) * 72 + ks * 32 + ((lane >> 4) << 3));
#pragma unroll
    for (int j = 0; j < 4; ++j) {
      bf16x8 bb = *(const bf16x8*)(Bl + (j * 16 + (lane & 15)) * 72 + ks * 32 + ((lane >> 4) << 3));
      acc[0][j] = __builtin_amdgcn_mfma_f32_16x16x32_bf16(a0, bb, acc[0][j], 0, 0, 0);
      acc[1][j] = __builtin_amdgcn_mfma_f32_16x16x32_bf16(a1, bb, acc[1][j], 0, 0, 0);
    }
  }
  const int r0 = wid * 32 + ((lane >> 4) << 2);
  const int cl = lane & 15;
#pragma unroll
  for (int i = 0; i < 2; ++i)
#pragma unroll
    for (int j = 0; j < 4; ++j)
#pragma unroll
      for (int r = 0; r < 4; ++r) {
        const int row = b * 4096 + mc * 128 + r0 + i * 16 + r;
        oat[(size_t)row * 1024 + h * 64 + j * 16 + cl] = acc[i][j][r];
      }
}

// ---------------- LayerNorm over C=1024, fp32 in -> bf16 out ----------------
__global__ __launch_bounds__(256)
void ln_k(const float* __restrict__ in, const float* __restrict__ g,
          const float* __restrict__ bb, short* __restrict__ out) {
  const int row = blockIdx.x;
  const int tid = threadIdx.x;
  const float4 v = ((const float4*)(in + (size_t)row * 1024))[tid];
  float s = v.x + v.y + v.z + v.w;
  float s2 = v.x * v.x + v.y * v.y + v.z * v.z + v.w * v.w;
#pragma unroll
  for (int o = 32; o > 0; o >>= 1) {
    s += __shfl_down(s, o);
    s2 += __shfl_down(s2, o);
  }
  __shared__ float red[8];
  const int wid = tid >> 6, lane = tid & 63;
  if (lane == 0) { red[wid] = s; red[wid + 4] = s2; }
  __syncthreads();
  const float ts = red[0] + red[1] + red[2] + red[3];
  const float ts2 = red[4] + red[5] + red[6] + red[7];
  const float mu = ts * (1.0f / 1024.0f);
  const float var = ts2 * (1.0f / 1024.0f) - mu * mu;
  const float rstd = rsqrtf(var + 1e-5f);
  const int c = tid * 4;
  s16x4 o;
  o[0] = f2bf((v.x - mu) * rstd * g[c + 0] + bb[c + 0]);
  o[1] = f2bf((v.y - mu) * rstd * g[c + 1] + bb[c + 1]);
  o[2] = f2bf((v.z - mu) * rstd * g[c + 2] + bb[c + 2]);
  o[3] = f2bf((v.w - mu) * rstd * g[c + 3] + bb[c + 3]);
  *(s16x4*)(out + (size_t)row * 1024 + c) = o;
}

extern "C" void kernel_launch(void* const* d_in, const int* in_sizes, int n_in,
                              void* d_out, int out_size, void* d_ws, size_t ws_size,
                              hipStream_t stream) {
  const float* x = (const float*)d_in[0];
  const float* Wq = (const float*)d_in[1];
  const float* bq = (const float*)d_in[2];
  const float* Wk = (const float*)d_in[3];
  const float* bk = (const float*)d_in[4];
  const float* Wv = (const float*)d_in[5];
  const float* bv = (const float*)d_in[6];
  const float* Wo = (const float*)d_in[7];
  const float* bo = (const float*)d_in[8];
  const float* lng = (const float*)d_in[9];
  const float* lnb = (const float*)d_in[10];

  char* ws = (char*)d_ws;
  short* xb = (short*)(ws + 0);              // 33554432 B  x bf16
  short* wt = (short*)(ws + 33554432);       // 12582912 B  6x (I+W)^T bf16
  short* q = (short*)(ws + 46137344);        // 33554432 B  q bf16
  short* kst = (short*)(ws + 79691776);      // 67108864 B  ks_t bf16 [k,b,h,d,n]
  short* vst = (short*)(ws + 146800640);     // 67108864 B  vs_t bf16 (contiguous after kst)
  float* P = (float*)(ws + 213909504);       //  8388608 B  state partials fp32
  short* stt = (short*)(ws + 222298112);     //   524288 B  state^T bf16
  short* ln = (short*)(ws + 146800640);      // reuse vst region (dead after states_k)
  float* oat = (float*)d_out;                // out_att scratch in d_out (overwritten by final GEMM)

  convx_k<<<4096, 256, 0, stream>>>(x, xb, 16777216 / 4);
  twc_k<<<dim3(32, 32, 6), dim3(32, 8), 0, stream>>>(Wq, Wk, Wv, Wo, wt);

  gemm256_k<0><<<1280, 512, 131072, stream>>>(xb, wt, bq, bk, bv, q, kst, nullptr);

  states_k<<<dim3(64, 4, 2), 256, 0, stream>>>(kst, vst, P);
  state_mul_k<<<64, 256, 0, stream>>>(P, stt);
  attn_k<<<dim3(32, 64), 256, 0, stream>>>(q, stt, oat);
  ln_k<<<16384, 256, 0, stream>>>(oat, lng, lnb, ln);
  gemm256_k<1><<<256, 512, 131072, stream>>>(ln, wt + 5242880, bo, nullptr, nullptr,
                                             nullptr, nullptr, (float*)d_out);
}